// Round 5
// baseline (162.529 us; speedup 1.0000x reference)
//
#include <hip/hip_runtime.h>
#include <cmath>

// CriticSNN forward, two-phase: BATCH=65536, STATE_DIM=6, HIDDEN=128, STEPS=8.
// Phase split halves per-block LDS (64 KiB table each) -> 2 blocks/CU ->
// 8 waves/SIMD (2x latency hiding vs the fused 128 KiB version), and halves
// each phase's serial per-step chain. spk1 ballots (128 B/elem, 8 MB) pass
// through d_ws. Walk/accumulation orders are bit-identical to the R1-verified
// kernel (absmax 0.0).

typedef unsigned long long u64;

constexpr int BATCH = 65536;
constexpr int HID   = 128;
constexpr int SDIM  = 6;
constexpr int NSTEP = 8;
constexpr int BLOCK = 1024;                         // 16 waves/block
constexpr int GRID  = 512;                          // 2 blocks/CU
constexpr int WAVES_TOTAL = GRID * (BLOCK / 64);    // 8192
constexpr int EPW   = BATCH / WAVES_TOTAL;          // 8 elems/wave

// ---------------- Phase A: layer 1, emit spk1 ballots ----------------
__global__ __launch_bounds__(BLOCK, 8) void snn_l1(
    const float* __restrict__ state,
    const float* __restrict__ w_fc1,
    const float* __restrict__ w_rec1,
    const float* __restrict__ p_a1, const float* __restrict__ p_b1,
    const float* __restrict__ p_t1,
    u64* __restrict__ masks)
{
    // entry(j,l) = {rec1[l][j], rec1[l+64][j]} at j*64+l: wave read at
    // (j<<6)|lane is a contiguous 512B block (2-way bank alias = free).
    __shared__ float2 ld_r1 [HID * 64];   // 64 KiB
    __shared__ float2 ld_fc1[SDIM * 64];  // 3 KiB

    const int tid = threadIdx.x;
    for (int v = tid; v < HID * 64; v += BLOCK) {
        const int l = v & 63, j = v >> 6;
        ld_r1[v] = make_float2(w_rec1[l * HID + j], w_rec1[(l + 64) * HID + j]);
    }
    for (int v = tid; v < SDIM * 64; v += BLOCK) {
        const int l = v & 63, k = v >> 6;
        ld_fc1[v] = make_float2(w_fc1[l * SDIM + k], w_fc1[(l + 64) * SDIM + k]);
    }
    const float a1 = fminf(fmaxf(p_a1[0], 0.f), 1.f);
    const float b1 = fminf(fmaxf(p_b1[0], 0.f), 1.f);
    const float t1 = p_t1[0];
    __syncthreads();

    const int lane = tid & 63;
    const int gw   = blockIdx.x * (BLOCK / 64) + (tid >> 6);

    for (int e = 0; e < EPW; ++e) {
        const int b = gw + WAVES_TOTAL * e;

        float cur_a = 0.f, cur_b = 0.f;
        #pragma unroll
        for (int k = 0; k < SDIM; ++k) {
            const float s = state[b * SDIM + k];      // wave-uniform s_load
            const float2 w = ld_fc1[(k << 6) | lane];
            cur_a = fmaf(s, w.x, cur_a);
            cur_b = fmaf(s, w.y, cur_b);
        }

        float syn1a = 0.f, syn1b = 0.f, mem1a = 0.f, mem1b = 0.f;
        bool  spk1a = false, spk1b = false;
        u64   mu = 0ull, mv = 0ull;
        u64* __restrict__ mp = masks + (size_t)b * (2 * NSTEP);

        #pragma unroll 1
        for (int t = 0; t < NSTEP; ++t) {
            // rec1 contribution from previous step's spikes (R1 order)
            float r_a = 0.f, r_b = 0.f;
            u64 m = mu;
            while (m) {
                const int j = __builtin_ctzll(m); m &= m - 1;
                const float2 w = ld_r1[(j << 6) | lane];
                r_a += w.x; r_b += w.y;
            }
            m = mv;
            while (m) {
                const int j = __builtin_ctzll(m) + 64; m &= m - 1;
                const float2 w = ld_r1[(j << 6) | lane];
                r_a += w.x; r_b += w.y;
            }
            syn1a = fmaf(a1, syn1a, cur_a + r_a);
            syn1b = fmaf(a1, syn1b, cur_b + r_b);
            mem1a = fmaf(b1, mem1a, syn1a) - (spk1a ? t1 : 0.f);
            mem1b = fmaf(b1, mem1b, syn1b) - (spk1b ? t1 : 0.f);
            spk1a = (mem1a - t1) > 0.f;
            spk1b = (mem1b - t1) > 0.f;
            mu = __ballot(spk1a);
            mv = __ballot(spk1b);
            if (lane == 0) { mp[2 * t] = mu; mp[2 * t + 1] = mv; }
        }
    }
}

// ---------------- Phase B: layer 2 + heads ----------------
__global__ __launch_bounds__(BLOCK, 8) void snn_l2(
    const float* __restrict__ w_fc2,
    const float* __restrict__ w_rec2,
    const float* __restrict__ w_mean,
    const float* __restrict__ w_std,
    const float* __restrict__ p_a2, const float* __restrict__ p_b2,
    const float* __restrict__ p_t2,
    const u64* __restrict__ masks,
    float* __restrict__ out)
{
    __shared__ float2 ld_f2[HID * 64];   // 64 KiB
    __shared__ float  ld_wm[HID];
    __shared__ float  ld_wsd[HID];

    const int tid = threadIdx.x;
    for (int v = tid; v < HID * 64; v += BLOCK) {
        const int l = v & 63, j = v >> 6;
        ld_f2[v] = make_float2(w_fc2[l * HID + j], w_fc2[(l + 64) * HID + j]);
    }
    if (tid < HID)          ld_wm [tid]       = w_mean[tid];
    else if (tid < 2 * HID) ld_wsd[tid - HID] = w_std [tid - HID];

    const float a2 = fminf(fmaxf(p_a2[0], 0.f), 1.f);
    const float b2 = fminf(fmaxf(p_b2[0], 0.f), 1.f);
    const float t2 = p_t2[0];
    __syncthreads();

    const int lane = tid & 63;
    const int gw   = blockIdx.x * (BLOCK / 64) + (tid >> 6);

    for (int e = 0; e < EPW; ++e) {
        const int b = gw + WAVES_TOTAL * e;

        // preload all 8 steps' spk1 ballots (wave-uniform -> s_load)
        u64 mu[NSTEP], mv[NSTEP];
        const u64* __restrict__ mp = masks + (size_t)b * (2 * NSTEP);
        #pragma unroll
        for (int t = 0; t < NSTEP; ++t) { mu[t] = mp[2 * t]; mv[t] = mp[2 * t + 1]; }

        // skip leading steps with no layer-1 spikes: all layer-2 state is
        // exactly zero through them (f=0, syn2=0, mem2=0, spk2=false).
        int t0 = 0;
        while (t0 < NSTEP && (mu[t0] | mv[t0]) == 0ull) ++t0;

        float syn2a = 0.f, syn2b = 0.f, mem2a = 0.f, mem2b = 0.f;
        float cnt_a = 0.f, cnt_b = 0.f;
        bool  spk2a = false, spk2b = false;
        u64   Ma = 0ull, Mb = 0ull;

        #pragma unroll 1
        for (int t = t0; t < NSTEP; ++t) {
            float f_a = 0.f, f_b = 0.f;
            u64 m = mu[t];
            while (m) {
                const int j = __builtin_ctzll(m); m &= m - 1;
                const float2 w = ld_f2[(j << 6) | lane];
                f_a += w.x; f_b += w.y;
            }
            m = mv[t];
            while (m) {
                const int j = __builtin_ctzll(m) + 64; m &= m - 1;
                const float2 w = ld_f2[(j << 6) | lane];
                f_a += w.x; f_b += w.y;
            }
            // rec2 from previous spk2 (almost never fires): global reads
            m = Ma;
            while (m) {
                const int j = __builtin_ctzll(m); m &= m - 1;
                f_a += w_rec2[lane * HID + j];
                f_b += w_rec2[(lane + 64) * HID + j];
            }
            m = Mb;
            while (m) {
                const int j = __builtin_ctzll(m) + 64; m &= m - 1;
                f_a += w_rec2[lane * HID + j];
                f_b += w_rec2[(lane + 64) * HID + j];
            }
            syn2a = fmaf(a2, syn2a, f_a);
            syn2b = fmaf(a2, syn2b, f_b);
            mem2a = fmaf(b2, mem2a, syn2a) - (spk2a ? t2 : 0.f);
            mem2b = fmaf(b2, mem2b, syn2b) - (spk2b ? t2 : 0.f);
            spk2a = (mem2a - t2) > 0.f;
            spk2b = (mem2b - t2) > 0.f;
            Ma = __ballot(spk2a);
            Mb = __ballot(spk2b);
            cnt_a += spk2a ? 1.f : 0.f;
            cnt_b += spk2b ? 1.f : 0.f;
        }

        // head: if NO lane of this wave saw any spk2 (the common case),
        // outputs are the exact constants tanh(0)=0 and 1.9*sig(2)+0.1.
        const bool any = (cnt_a != 0.f) || (cnt_b != 0.f);
        if (__ballot(any) == 0ull) {
            if (lane == 0) {
                out[b] = 0.f;
                const float sg = 1.f / (1.f + expf(-2.0f));
                out[BATCH + b] = 1.9f * sg + 0.1f;
            }
        } else {
            const float avg_a = cnt_a * 0.125f;
            const float avg_b = cnt_b * 0.125f;
            float dm = avg_a * ld_wm [lane] + avg_b * ld_wm [lane + 64];
            float ds = avg_a * ld_wsd[lane] + avg_b * ld_wsd[lane + 64];
            #pragma unroll
            for (int off = 32; off > 0; off >>= 1) {
                dm += __shfl_xor(dm, off, 64);
                ds += __shfl_xor(ds, off, 64);
            }
            if (lane == 0) {
                out[b] = tanhf(dm);
                const float sg = 1.f / (1.f + expf(-(ds + 2.f)));
                out[BATCH + b] = 1.9f * sg + 0.1f;
            }
        }
    }
}

extern "C" void kernel_launch(void* const* d_in, const int* in_sizes, int n_in,
                              void* d_out, int out_size, void* d_ws, size_t ws_size,
                              hipStream_t stream) {
    (void)in_sizes; (void)n_in; (void)out_size; (void)ws_size;
    u64* masks = (u64*)d_ws;   // BATCH * 2 * NSTEP u64 = 8 MB
    snn_l1<<<GRID, BLOCK, 0, stream>>>(
        (const float*)d_in[0],   // state
        (const float*)d_in[1],   // w_fc1
        (const float*)d_in[2],   // w_rec1
        (const float*)d_in[7],   // alpha1
        (const float*)d_in[8],   // beta1
        (const float*)d_in[9],   // thr1
        masks);
    snn_l2<<<GRID, BLOCK, 0, stream>>>(
        (const float*)d_in[3],   // w_fc2
        (const float*)d_in[4],   // w_rec2
        (const float*)d_in[5],   // w_mean
        (const float*)d_in[6],   // w_std
        (const float*)d_in[10],  // alpha2
        (const float*)d_in[11],  // beta2
        (const float*)d_in[12],  // thr2
        masks,
        (float*)d_out);
}

// Round 6
// 141.206 us; speedup vs baseline: 1.1510x; 1.1510x over previous
//
#include <hip/hip_runtime.h>
#include <cmath>

// CriticSNN forward: BATCH=65536, STATE_DIM=6, HIDDEN=128, NUM_STEPS=8, OUT=1
// One wave per batch element; lane l owns neurons l and l+64.
// Spikes -> wave ballots; matmuls -> masked column sums from LDS.
// R6 = R1's proven structure + two surgical changes:
//  (a) fused float4 table {rec1_a, rec1_b, fc2_a, fc2_b}: each spk1 bit is
//      walked ONCE per step (one ds_read_b128 serves fc2-now and rec1-next),
//  (b) pair-batched walk: two loads issued per iteration -> one LDS latency
//      window per 2 bits instead of per bit.
// Accumulation order (j ascending, u-bits then v-bits) is bit-identical to
// the R1-verified kernel (absmax 0.0).

typedef float v2f __attribute__((ext_vector_type(2)));
typedef float v4f __attribute__((ext_vector_type(4)));
typedef unsigned long long u64;

constexpr int BATCH = 65536;
constexpr int HID   = 128;
constexpr int SDIM  = 6;
constexpr int NSTEP = 8;
constexpr int BLOCK = 1024;                         // 16 waves/block
constexpr int GRID  = 256;                          // 1 block per CU
constexpr int WAVES_TOTAL = GRID * (BLOCK / 64);    // 4096
constexpr int EPW   = BATCH / WAVES_TOTAL;          // 16 elems/wave

__global__ __launch_bounds__(BLOCK) void snn_fwd(
    const float* __restrict__ state,
    const float* __restrict__ w_fc1,
    const float* __restrict__ w_rec1,
    const float* __restrict__ w_fc2,
    const float* __restrict__ w_rec2,
    const float* __restrict__ w_mean,
    const float* __restrict__ w_std,
    const float* __restrict__ p_a1, const float* __restrict__ p_b1,
    const float* __restrict__ p_t1,
    const float* __restrict__ p_a2, const float* __restrict__ p_b2,
    const float* __restrict__ p_t2,
    float* __restrict__ out)
{
    // entry(j,l) = {rec1[l][j], rec1[l+64][j], fc2[l][j], fc2[l+64][j]}
    // at plain index j*64+l: wave read (j<<6)|lane is a contiguous 1KB block
    // -> conflict-free ds_read_b128, one v_add of scalar j*1024 per load.
    __shared__ v4f   ld_w [HID * 64];    // 128 KiB
    __shared__ float2 ld_fc1[SDIM * 64]; // 3 KiB
    __shared__ float ld_wm[HID];
    __shared__ float ld_wsd[HID];

    const int tid = threadIdx.x;

    for (int v = tid; v < HID * 64; v += BLOCK) {
        const int l = v & 63, j = v >> 6;
        ld_w[v] = (v4f){ w_rec1[l * HID + j], w_rec1[(l + 64) * HID + j],
                         w_fc2 [l * HID + j], w_fc2 [(l + 64) * HID + j] };
    }
    for (int v = tid; v < SDIM * 64; v += BLOCK) {
        const int l = v & 63, k = v >> 6;
        ld_fc1[v] = make_float2(w_fc1[l * SDIM + k], w_fc1[(l + 64) * SDIM + k]);
    }
    if (tid < HID)          ld_wm [tid]       = w_mean[tid];
    else if (tid < 2 * HID) ld_wsd[tid - HID] = w_std [tid - HID];

    const float a1 = fminf(fmaxf(p_a1[0], 0.f), 1.f);
    const float b1 = fminf(fmaxf(p_b1[0], 0.f), 1.f);
    const float a2 = fminf(fmaxf(p_a2[0], 0.f), 1.f);
    const float b2 = fminf(fmaxf(p_b2[0], 0.f), 1.f);
    const float t1 = p_t1[0];
    const float t2 = p_t2[0];

    __syncthreads();

    const int lane = tid & 63;
    const int gw   = blockIdx.x * (BLOCK / 64) + (tid >> 6);

    for (int e = 0; e < EPW; ++e) {
        const int b = gw + WAVES_TOTAL * e;

        float cur_a = 0.f, cur_b = 0.f;
        #pragma unroll
        for (int k = 0; k < SDIM; ++k) {
            const float s = state[b * SDIM + k];          // wave-broadcast
            const float2 w = ld_fc1[(k << 6) | lane];
            cur_a = fmaf(s, w.x, cur_a);
            cur_b = fmaf(s, w.y, cur_b);
        }

        float syn1a = 0.f, syn1b = 0.f, mem1a = 0.f, mem1b = 0.f;
        float syn2a = 0.f, syn2b = 0.f, mem2a = 0.f, mem2b = 0.f;
        bool  spk1a = false, spk1b = false, spk2a = false, spk2b = false;
        float cnt_a = 0.f, cnt_b = 0.f;
        u64   m2a = 0ull, m2b = 0ull;
        v2f   rr = {0.f, 0.f};           // rec1 contribution for the NEXT step

        #pragma unroll 1
        for (int t = 0; t < NSTEP; ++t) {
            // ----- layer 1 state update (rr computed during step t-1) -----
            syn1a = fmaf(a1, syn1a, cur_a + rr.x);
            syn1b = fmaf(a1, syn1b, cur_b + rr.y);
            mem1a = fmaf(b1, mem1a, syn1a) - (spk1a ? t1 : 0.f);
            mem1b = fmaf(b1, mem1b, syn1b) - (spk1b ? t1 : 0.f);
            spk1a = (mem1a - t1) > 0.f;
            spk1b = (mem1b - t1) > 0.f;
            const u64 mu = __ballot(spk1a);
            const u64 mv = __ballot(spk1b);

            // ----- fused pair-batched walk over new spk1 bits -----
            // one ds_read_b128 per bit gives {rec1_next (lo), fc2_now (hi)};
            // two loads issued per iteration -> one latency window per pair.
            rr = (v2f){0.f, 0.f};
            v2f ff = {0.f, 0.f};
            u64 m = mu;
            while (m) {
                const int j0 = __builtin_ctzll(m); m &= m - 1;
                if (m) {
                    const int j1 = __builtin_ctzll(m); m &= m - 1;
                    const v4f w0 = ld_w[(j0 << 6) | lane];
                    const v4f w1 = ld_w[(j1 << 6) | lane];
                    rr += w0.lo; ff += w0.hi;
                    rr += w1.lo; ff += w1.hi;
                } else {
                    const v4f w0 = ld_w[(j0 << 6) | lane];
                    rr += w0.lo; ff += w0.hi;
                }
            }
            m = mv;
            while (m) {
                const int j0 = __builtin_ctzll(m) + 64; m &= m - 1;
                if (m) {
                    const int j1 = __builtin_ctzll(m) + 64; m &= m - 1;
                    const v4f w0 = ld_w[(j0 << 6) | lane];
                    const v4f w1 = ld_w[(j1 << 6) | lane];
                    rr += w0.lo; ff += w0.hi;
                    rr += w1.lo; ff += w1.hi;
                } else {
                    const v4f w0 = ld_w[(j0 << 6) | lane];
                    rr += w0.lo; ff += w0.hi;
                }
            }

            // ----- rec2 from PREVIOUS spk2 (almost never fires): global -----
            float f_a = ff.x, f_b = ff.y;
            m = m2a;
            while (m) {
                const int j = __builtin_ctzll(m); m &= m - 1;
                f_a += w_rec2[lane * HID + j];
                f_b += w_rec2[(lane + 64) * HID + j];
            }
            m = m2b;
            while (m) {
                const int j = __builtin_ctzll(m) + 64; m &= m - 1;
                f_a += w_rec2[lane * HID + j];
                f_b += w_rec2[(lane + 64) * HID + j];
            }

            // ----- layer 2 state update -----
            syn2a = fmaf(a2, syn2a, f_a);
            syn2b = fmaf(a2, syn2b, f_b);
            mem2a = fmaf(b2, mem2a, syn2a) - (spk2a ? t2 : 0.f);
            mem2b = fmaf(b2, mem2b, syn2b) - (spk2b ? t2 : 0.f);
            spk2a = (mem2a - t2) > 0.f;
            spk2b = (mem2b - t2) > 0.f;
            m2a = __ballot(spk2a);
            m2b = __ballot(spk2b);
            cnt_a += spk2a ? 1.f : 0.f;
            cnt_b += spk2b ? 1.f : 0.f;
        }

        // ----- head -----
        const float avg_a = cnt_a * 0.125f;
        const float avg_b = cnt_b * 0.125f;
        float dm = avg_a * ld_wm [lane] + avg_b * ld_wm [lane + 64];
        float ds = avg_a * ld_wsd[lane] + avg_b * ld_wsd[lane + 64];
        #pragma unroll
        for (int off = 32; off > 0; off >>= 1) {
            dm += __shfl_xor(dm, off, 64);
            ds += __shfl_xor(ds, off, 64);
        }
        if (lane == 0) {
            out[b] = tanhf(dm);
            const float sg = 1.f / (1.f + expf(-(ds + 2.f)));
            out[BATCH + b] = 1.9f * sg + 0.1f;
        }
    }
}

extern "C" void kernel_launch(void* const* d_in, const int* in_sizes, int n_in,
                              void* d_out, int out_size, void* d_ws, size_t ws_size,
                              hipStream_t stream) {
    (void)in_sizes; (void)n_in; (void)d_ws; (void)ws_size; (void)out_size;
    snn_fwd<<<GRID, BLOCK, 0, stream>>>(
        (const float*)d_in[0],   // state
        (const float*)d_in[1],   // w_fc1
        (const float*)d_in[2],   // w_rec1
        (const float*)d_in[3],   // w_fc2
        (const float*)d_in[4],   // w_rec2
        (const float*)d_in[5],   // w_mean
        (const float*)d_in[6],   // w_std
        (const float*)d_in[7],   // alpha1
        (const float*)d_in[8],   // beta1
        (const float*)d_in[9],   // thr1
        (const float*)d_in[10],  // alpha2
        (const float*)d_in[11],  // beta2
        (const float*)d_in[12],  // thr2
        (float*)d_out);
}